// Round 12
// baseline (363.859 us; speedup 1.0000x reference)
//
#include <hip/hip_runtime.h>

#define NN 50000
#define NE 800000
#define NG 2048
#define F 64

constexpr int NB = (NN + 255) / 256;  // 196 scan chunks

typedef float f4 __attribute__((ext_vector_type(4)));

static __device__ __forceinline__ int ntload_i(const int* p) {
    return __builtin_nontemporal_load(p);
}

// ---------------- degree (edge-only in-degree) ----------------
__global__ void deg_kernel(const int* __restrict__ dst, int* __restrict__ deg) {
    int e = blockIdx.x * 256 + threadIdx.x;
    if (e < NE) atomicAdd(&deg[ntload_i(&dst[e])], 1);
}

// dinv[v] = rsqrt(deg+1); xd HALF-MAJOR [2][NN][16]: half h, node v, feats h*16..h*16+15
__global__ void scalex_kernel(const int* __restrict__ deg, const f4* __restrict__ x4,
                              float* __restrict__ dinv, f4* __restrict__ xdh) {
    int i = blockIdx.x * 256 + threadIdx.x;   // f4 index over NN*8
    if (i < NN * 8) {
        int v = i >> 3, ff = i & 7;
        float d = rsqrtf((float)(deg[v] + 1));
        if (ff == 0) dinv[v] = d;
        f4 a = x4[i];
        int h = ff >> 2, fj = ff & 3;
        xdh[((long)h * NN + v) * 4 + fj] = d * a;
    }
}

// ---------------- scan: chunk sums, then fused (scan-of-sums + chunk scan) --------
__global__ void scan1_kernel(const int* __restrict__ deg, int* __restrict__ bsums) {
    __shared__ int s[256];
    int t = threadIdx.x, i = blockIdx.x * 256 + t;
    s[t] = (i < NN) ? deg[i] : 0;
    __syncthreads();
    for (int off = 128; off > 0; off >>= 1) {
        if (t < off) s[t] += s[t + off];
        __syncthreads();
    }
    if (t == 0) bsums[blockIdx.x] = s[0];
}

__global__ void scan23_kernel(const int* __restrict__ deg, const int* __restrict__ bsums,
                              int* __restrict__ rowptr, int* __restrict__ cursor) {
    __shared__ int offs[256];
    __shared__ int s[256];
    int t = threadIdx.x, blk = blockIdx.x;
    offs[t] = (t < NB) ? bsums[t] : 0;
    __syncthreads();
    for (int o = 1; o < 256; o <<= 1) {
        int x = (t >= o) ? offs[t - o] : 0;
        __syncthreads();
        offs[t] += x;
        __syncthreads();
    }
    int chunk_off = (blk > 0) ? offs[blk - 1] : 0;
    int i = blk * 256 + t;
    int v = (i < NN) ? deg[i] : 0;
    s[t] = v;
    __syncthreads();
    for (int o = 1; o < 256; o <<= 1) {
        int x = (t >= o) ? s[t - o] : 0;
        __syncthreads();
        s[t] += x;
        __syncthreads();
    }
    if (i < NN) {
        int rp = chunk_off + s[t] - v;
        rowptr[i] = rp;
        cursor[i] = rp;
    }
    if (blk == 0 && t == 0) rowptr[NN] = NE;
}

__global__ void fill_kernel(const int* __restrict__ src, const int* __restrict__ dst,
                            int* __restrict__ cursor, unsigned short* __restrict__ col) {
    int e = blockIdx.x * 256 + threadIdx.x;
    if (e < NE) {
        int sv = ntload_i(&src[e]);
        int slot = atomicAdd(&cursor[ntload_i(&dst[e])], 1);
        col[slot] = (unsigned short)sv;
    }
}

// ---------------- agg32h: half-split layer-1 agg, 16 nodes per wave ----------------
// xd half-major [2][NN][16]; half h pinned to XCDs {4h..4h+3} via bi&7.
// grid 1568: h=(bi&7)>>2, sub=((bi>>3)<<2)|(bi&3) in [0,784); out sbuf row-major [NN][32].
__global__ void agg32h_kernel(const f4* __restrict__ xdh, const int* __restrict__ rowptr,
                              const unsigned short* __restrict__ col, const float* __restrict__ dinv,
                              float* __restrict__ out) {
    int tid = threadIdx.x, lane = tid & 63, w = tid >> 6;
    int bi = blockIdx.x;
    int h = (bi & 7) >> 2;
    int sub = ((bi >> 3) << 2) | (bi & 3);
    int base = sub * 64 + w * 16;
    if (base >= NN) return;
    int slot = lane >> 2, fj = lane & 3;   // 16 edge slots x 4 f4-lanes (16 feats)
    const f4* gb = xdh + (long)h * NN * 4;
    int li = base + ((lane < 17) ? lane : 16);
    if (li > NN) li = NN;
    int rpv = rowptr[li];
#pragma unroll 1
    for (int i = 0; i < 16; ++i) {
        int v = base + i;
        if (v >= NN) break;
        int beg = __shfl(rpv, i), end = __shfl(rpv, i + 1);
        f4 acc = {0.f, 0.f, 0.f, 0.f};
        for (int b0 = beg; b0 < end; b0 += 32) {
            f4 a[2];
            float wt[2];
#pragma unroll
            for (int j = 0; j < 2; ++j) {
                int e = b0 + slot + j * 16;
                int ce = (e < end) ? e : (end - 1);
                wt[j] = (e < end) ? 1.f : 0.f;
                int u = col[ce];
                a[j] = gb[(long)u * 4 + fj];   // 64B from pinned contiguous half-plane
            }
            acc += wt[0] * a[0] + wt[1] * a[1];
        }
#pragma unroll
        for (int m = 4; m < 64; m <<= 1) {
            acc.x += __shfl_xor(acc.x, m);
            acc.y += __shfl_xor(acc.y, m);
            acc.z += __shfl_xor(acc.z, m);
            acc.w += __shfl_xor(acc.w, m);
        }
        f4 self = gb[(long)v * 4 + fj];
        float d = dinv[v];
        acc = d * (acc + self);
        if (slot < 4) {   // 16 scalars = one 64B line
            float comp = (slot == 0) ? acc.x : (slot == 1) ? acc.y : (slot == 2) ? acc.z : acc.w;
            out[(long)v * 32 + h * 16 + fj * 4 + slot] = comp;
        }
    }
}

// ---------------- agg4q: quarter-split agg, 16 nodes per wave ----------------------
// g quarter-major [4][NN][16]; quarter q pinned to XCD pair {2q,2q+1} via bi&7.
// grid 3136: q=(bi&7)>>1, sub=((bi>>3)<<1)|(bi&1) in [0,784).
template <bool POOL>
__global__ void agg4q_kernel(const f4* __restrict__ gq, const int* __restrict__ rowptr,
                             const unsigned short* __restrict__ col, const float* __restrict__ dinv,
                             const f4* __restrict__ bias4, float* __restrict__ out,
                             const int* __restrict__ batch, float* __restrict__ pooled,
                             float* __restrict__ counts) {
    int tid = threadIdx.x, lane = tid & 63, w = tid >> 6;
    int bi = blockIdx.x;
    int q = (bi & 7) >> 1;
    int sub = ((bi >> 3) << 1) | (bi & 1);
    int base = sub * 64 + w * 16;
    if (base >= NN) return;
    int slot = lane >> 2, fj = lane & 3;   // 16 edge slots x 4 f4-lanes (16 feats)
    const f4* gb = gq + (long)q * NN * 4;
    int li = base + ((lane < 17) ? lane : 16);
    if (li > NN) li = NN;
    int rpv = rowptr[li];
#pragma unroll 1
    for (int i = 0; i < 16; ++i) {
        int v = base + i;
        if (v >= NN) break;
        int beg = __shfl(rpv, i), end = __shfl(rpv, i + 1);
        f4 acc = {0.f, 0.f, 0.f, 0.f};
        for (int b0 = beg; b0 < end; b0 += 32) {
            f4 a[2];
            float wt[2];
#pragma unroll
            for (int j = 0; j < 2; ++j) {
                int e = b0 + slot + j * 16;
                int ce = (e < end) ? e : (end - 1);
                wt[j] = (e < end) ? 1.f : 0.f;
                int u = col[ce];
                a[j] = gb[(long)u * 4 + fj];   // 64B from pinned contiguous quarter-plane
            }
            acc += wt[0] * a[0] + wt[1] * a[1];
        }
#pragma unroll
        for (int m = 4; m < 64; m <<= 1) {
            acc.x += __shfl_xor(acc.x, m);
            acc.y += __shfl_xor(acc.y, m);
            acc.z += __shfl_xor(acc.z, m);
            acc.w += __shfl_xor(acc.w, m);
        }
        f4 self = gb[(long)v * 4 + fj];
        float d = dinv[v];
        f4 bb = bias4[q * 4 + fj];
        f4 hv;
        hv.x = fmaxf(fmaf(d, acc.x + self.x, bb.x), 0.f);
        hv.y = fmaxf(fmaf(d, acc.y + self.y, bb.y), 0.f);
        hv.z = fmaxf(fmaf(d, acc.z + self.z, bb.z), 0.f);
        hv.w = fmaxf(fmaf(d, acc.w + self.w, bb.w), 0.f);
        if (slot < 4) {   // 16 scalars = one 64B line
            float comp = (slot == 0) ? hv.x : (slot == 1) ? hv.y : (slot == 2) ? hv.z : hv.w;
            int feat = q * 16 + fj * 4 + slot;
            if (POOL) {
                atomicAdd(&pooled[(long)batch[v] * F + feat], comp);
            } else {
                out[(long)v * F + feat] = comp;
            }
        }
        if (POOL && q == 0 && lane == 0) atomicAdd(&counts[batch[v]], 1.0f);
    }
}

// ---------------- GEMM: 16 nodes/block, 256 threads -------------------------------
// RELU_BIAS: out = relu(in@W + b), row-major (layer-1)
// else:      out = dinv[n]*(in@W), QUARTER-MAJOR [4][NN][16] for agg4q
template <int K, bool RELU_BIAS>
__global__ void gemm_kernel(const float* __restrict__ in, const float* __restrict__ W,
                            const float* __restrict__ bias, const float* __restrict__ dinv,
                            float* __restrict__ out) {
    __shared__ float Ws[K * F];
    int t = threadIdx.x;
#pragma unroll
    for (int i = 0; i < K * F / 256; ++i) Ws[i * 256 + t] = W[i * 256 + t];
    __syncthreads();
    int f = t & 63;
    int slot = __builtin_amdgcn_readfirstlane(t >> 6);  // wave-uniform
    int n0 = blockIdx.x * 16 + slot;                    // nodes n0, n0+4, n0+8, n0+12
    float acc0 = 0.f, acc1 = 0.f, acc2 = 0.f, acc3 = 0.f;
    const float* r0 = in + (long)n0 * K;
    const float* r1 = r0 + 4 * K;
    const float* r2 = r0 + 8 * K;
    const float* r3 = r0 + 12 * K;
#pragma unroll
    for (int k = 0; k < K; ++k) {
        float w = Ws[k * F + f];
        acc0 = fmaf(r0[k], w, acc0);
        acc1 = fmaf(r1[k], w, acc1);
        acc2 = fmaf(r2[k], w, acc2);
        acc3 = fmaf(r3[k], w, acc3);
    }
    if (RELU_BIAS) {
        float b = bias[f];
        out[(long)n0 * F + f]        = fmaxf(acc0 + b, 0.f);
        out[(long)(n0 + 4) * F + f]  = fmaxf(acc1 + b, 0.f);
        out[(long)(n0 + 8) * F + f]  = fmaxf(acc2 + b, 0.f);
        out[(long)(n0 + 12) * F + f] = fmaxf(acc3 + b, 0.f);
    } else {
        int q = f >> 4, fl = f & 15;
        float* o = out + (long)q * NN * 16 + fl;
        o[(long)n0 * 16]        = dinv[n0] * acc0;
        o[(long)(n0 + 4) * 16]  = dinv[n0 + 4] * acc1;
        o[(long)(n0 + 8) * 16]  = dinv[n0 + 8] * acc2;
        o[(long)(n0 + 12) * 16] = dinv[n0 + 12] * acc3;
    }
}

// ---------------- head: out = relu(pooled/cnt @ lw1 + lb1) @ lw2 + lb2 ------------
__global__ void head_kernel(const float* __restrict__ pooled, const float* __restrict__ counts,
                            const float* __restrict__ lw1, const float* __restrict__ lb1,
                            const float* __restrict__ lw2, const float* __restrict__ lb2,
                            float* __restrict__ out) {
    __shared__ float p[F];
    __shared__ float hid[F];
    int gid = blockIdx.x, t = threadIdx.x;
    float cnt = fmaxf(counts[gid], 1.0f);
    p[t] = pooled[(long)gid * F + t] / cnt;
    __syncthreads();
    float acc = lb1[t];
#pragma unroll 8
    for (int k = 0; k < F; ++k) acc = fmaf(p[k], lw1[k * F + t], acc);
    hid[t] = fmaxf(acc, 0.f);
    __syncthreads();
    if (t < 2) {
        float a = lb2[t];
#pragma unroll 8
        for (int k = 0; k < F; ++k) a = fmaf(hid[k], lw2[k * 2 + t], a);
        out[(long)gid * 2 + t] = a;
    }
}

extern "C" void kernel_launch(void* const* d_in, const int* in_sizes, int n_in,
                              void* d_out, int out_size, void* d_ws, size_t ws_size,
                              hipStream_t stream) {
    const float* x    = (const float*)d_in[0];
    const int*   ei   = (const int*)d_in[1];   // [2, NE]: src then dst
    const int*   bat  = (const int*)d_in[2];
    const float* W1   = (const float*)d_in[3];
    const float* b1   = (const float*)d_in[4];
    const float* W2   = (const float*)d_in[5];
    const float* b2   = (const float*)d_in[6];
    const float* W3   = (const float*)d_in[7];
    const float* b3   = (const float*)d_in[8];
    const float* lw1  = (const float*)d_in[9];
    const float* lb1  = (const float*)d_in[10];
    const float* lw2  = (const float*)d_in[11];
    const float* lb2  = (const float*)d_in[12];
    float* out = (float*)d_out;

    const int* src = ei;
    const int* dst = ei + NE;

    // workspace carve-up (256B aligned)
    char* ws = (char*)d_ws;
    size_t off = 0;
    auto carve = [&](size_t bytes) {
        void* p = ws + off;
        off += (bytes + 255) & ~(size_t)255;
        return p;
    };
    int*   deg     = (int*)carve(NN * 4);
    float* dinv    = (float*)carve(NN * 4);
    int*   rowptr  = (int*)carve((NN + 1) * 4);
    int*   cursor  = (int*)carve(NN * 4);
    int*   bsums   = (int*)carve(256 * 4);
    unsigned short* col = (unsigned short*)carve((size_t)NE * 2);
    float* xd      = (float*)carve((size_t)NN * 32 * 4);  // half-major [2][NN][16]
    float* sbuf    = (float*)carve((size_t)NN * 32 * 4);  // row-major
    float* bufA    = (float*)carve((size_t)NN * F * 4);   // row-major h
    float* bufB    = (float*)carve((size_t)NN * F * 4);   // quarter-major g [4][NN][16]
    float* pooled  = (float*)carve((size_t)NG * F * 4 + NG * 4);
    float* counts  = pooled + (size_t)NG * F;

    hipMemsetAsync(deg, 0, NN * 4, stream);
    hipMemsetAsync(pooled, 0, ((size_t)NG * F + NG) * 4, stream);

    deg_kernel<<<(NE + 255) / 256, 256, 0, stream>>>(dst, deg);
    scalex_kernel<<<(NN * 8 + 255) / 256, 256, 0, stream>>>(deg, (const f4*)x, dinv, (f4*)xd);
    scan1_kernel<<<NB, 256, 0, stream>>>(deg, bsums);
    scan23_kernel<<<NB, 256, 0, stream>>>(deg, bsums, rowptr, cursor);
    fill_kernel<<<(NE + 255) / 256, 256, 0, stream>>>(src, dst, cursor, col);

    const int gridH = 8 * 196;     // 1568 blocks (agg32h: 2 halves x 784 subs)
    const int gridQ = 8 * 392;     // 3136 blocks (agg4q: 4 quarters x 784 subs)
    const int gridG = NN / 16;     // 3125 blocks (gemm)

    // layer 1: half-split agg of xd, then GEMM with fused bias+relu
    agg32h_kernel<<<gridH, 256, 0, stream>>>((const f4*)xd, rowptr, col, dinv, sbuf);
    gemm_kernel<32, true><<<gridG, 256, 0, stream>>>(sbuf, W1, b1, dinv, bufA);

    // layer 2: g = dinv*(h1@W2) quarter-major; quarter-split 16-node agg
    gemm_kernel<64, false><<<gridG, 256, 0, stream>>>(bufA, W2, nullptr, dinv, bufB);
    agg4q_kernel<false><<<gridQ, 256, 0, stream>>>((const f4*)bufB, rowptr, col, dinv,
                                                   (const f4*)b2, bufA,
                                                   nullptr, nullptr, nullptr);
    // layer 3: same, final fuses mean-pool atomics
    gemm_kernel<64, false><<<gridG, 256, 0, stream>>>(bufA, W3, nullptr, dinv, bufB);
    agg4q_kernel<true><<<gridQ, 256, 0, stream>>>((const f4*)bufB, rowptr, col, dinv,
                                                  (const f4*)b3, nullptr,
                                                  bat, pooled, counts);
    // head MLP
    head_kernel<<<NG, 64, 0, stream>>>(pooled, counts, lw1, lb1, lw2, lb2, out);
}